// Round 16
// baseline (5426.580 us; speedup 1.0000x reference)
//
#include <hip/hip_runtime.h>

namespace {

constexpr int NB = 16, HH = 128, WW = 128, KK = 512, DD = 128;
constexpr int NPIX = NB * HH * WW;        // 262144
constexpr int NELEM = NPIX * DD;          // 33554432
constexpr int XRECON = NB * 3 * HH * WW;  // 786432
constexpr int VQ_BLK_PX = 64;
constexpr int VQ_BLOCKS = NPIX / VQ_BLK_PX;  // 4096

using bf16x8 = __attribute__((ext_vector_type(8))) short;
using f32x4 = __attribute__((ext_vector_type(4))) float;

__device__ __forceinline__ ushort f2bf(float f) {
  unsigned u = __float_as_uint(f);
  return (ushort)((u + 0x7FFFu + ((u >> 16) & 1u)) >> 16);  // RNE
}

// ---------- zero the code-usage histogram (lives in d_out scratch) ----------
__global__ void zero_counts(int* __restrict__ counts) {
  const int t = threadIdx.x;
  counts[t] = 0;
  counts[t + 256] = 0;
}

// swizzle preserving 8B alignment at even px: phys = px + (px>>5)*4
__device__ __forceinline__ int swz(int px) { return px + ((px >> 5) << 2); }

// ---------- fp32 weight repack: w -> wr[ci][tap][oc] (encoder) ----------
__global__ void repack_w(const float* __restrict__ w, float* __restrict__ wr) {
  int i = blockIdx.x * 256 + threadIdx.x;  // over 128*9*128
  int oc = i & 127;
  int tap = (i >> 7) % 9;
  int ci = i / (9 * 128);
  wr[i] = w[(oc * 128 + ci) * 9 + tap];
}

// ---------- bf16 weight repack (decoder, TRANS flip): wr[tap][ci/8][oc][8] ----------
__global__ void repack_wb16(const float* __restrict__ w, ushort* __restrict__ wr) {
  int i = blockIdx.x * 256 + threadIdx.x;  // 9*16*128*8 = 147456
  int j = i & 7;
  int oc = (i >> 3) & 127;
  int cib = (i >> 10) & 15;
  int tap = i >> 14;
  int ci = cib * 8 + j;
  int ky = tap / 3, kx = tap % 3;
  float v = w[((size_t)ci * 128 + oc) * 9 + (2 - ky) * 3 + (2 - kx)];
  wr[i] = f2bf(v);
}

// ---------- 3x3 conv 128->128 fp32, scalar-weight path (encoder) ----------
// CT=8 + bounds(256,6): 14.2 KB LDS, 6 blocks/CU = 24 waves for latency hiding.
// Per-output FMA chain ci->r->dx ascending: BIT-IDENTICAL to r9-r15.
template <int CT>
__global__ __launch_bounds__(256, 6) void conv3x3_s(
    const float* __restrict__ in, const float* __restrict__ wr,
    const float* __restrict__ bias, float* __restrict__ out) {
  __shared__ __align__(16) float s_in[CT][3][148];
  const int tid = threadIdx.x;
  const int b = blockIdx.x >> 7;
  const int y = blockIdx.x & 127;
  const int lane = tid & 63;
  const int wv = __builtin_amdgcn_readfirstlane(tid >> 6);
  const int oc0 = wv << 5;
  const int px0 = lane << 1;

  float acc[32][2];
#pragma unroll
  for (int k = 0; k < 32; ++k) { acc[k][0] = 0.f; acc[k][1] = 0.f; }

  const int f_lo = swz(px0);
  const int f_hi = swz(px0 + 2);

#pragma unroll 1
  for (int ci0 = 0; ci0 < 128; ci0 += CT) {
    for (int i = tid; i < CT * 390; i += 256) {
      int ci = i / 390;
      int rem = i - ci * 390;
      int r = rem / 130;
      int px = rem - r * 130;
      int yy = y + r - 1;
      int xx = px - 1;
      float v = 0.f;
      if (yy >= 0 && yy < HH && xx >= 0 && xx < WW)
        v = in[((b * 128 + ci0 + ci) * HH + yy) * WW + xx];
      s_in[ci][r][swz(px)] = v;
    }
    __syncthreads();
#pragma unroll 1
    for (int ci = 0; ci < CT; ++ci) {
      float ind[3][4];
#pragma unroll
      for (int r = 0; r < 3; ++r) {
        float2 a = *reinterpret_cast<const float2*>(&s_in[ci][r][f_lo]);
        float2 c = *reinterpret_cast<const float2*>(&s_in[ci][r][f_hi]);
        ind[r][0] = a.x; ind[r][1] = a.y; ind[r][2] = c.x; ind[r][3] = c.y;
      }
      const float* wp = wr + (size_t)(ci0 + ci) * 9 * 128 + oc0;
#pragma unroll
      for (int r = 0; r < 3; ++r) {
#pragma unroll
        for (int dx = 0; dx < 3; ++dx) {
          const float* wt = wp + (r * 3 + dx) * 128;
          float ws[32];
#pragma unroll
          for (int k = 0; k < 32; ++k) ws[k] = wt[k];
          float v0 = ind[r][dx], v1 = ind[r][dx + 1];
#pragma unroll
          for (int k = 0; k < 32; ++k) {
            acc[k][0] = __fmaf_rn(ws[k], v0, acc[k][0]);
            acc[k][1] = __fmaf_rn(ws[k], v1, acc[k][1]);
          }
        }
      }
    }
    __syncthreads();
  }
#pragma unroll
  for (int k = 0; k < 32; ++k) {
    int oc = oc0 + k;
    float bv = bias[oc];
    float2 v = {acc[k][0] + bv, acc[k][1] + bv};
    *reinterpret_cast<float2*>(out + ((b * 128 + oc) * HH + y) * WW + px0) = v;
  }
}

// ---------- layer-1 conv 3->128, fp64 acc (r14-proven, spill-free) ----------
__global__ __launch_bounds__(256, 3) void conv_l1(
    const float* __restrict__ in, const float* __restrict__ w,
    const float* __restrict__ bias, float* __restrict__ out) {
  __shared__ __align__(16) double s_in[3][3][74];
  __shared__ __align__(16) float s_w[27][132];
  const int tid = threadIdx.x;
  const int b = blockIdx.x >> 8;
  const int y = (blockIdx.x >> 1) & 127;
  const int x0base = (blockIdx.x & 1) << 6;
  const int ocg = tid >> 3;
  const int pxg = tid & 7;
  const int x0 = pxg * 8;
  const int f0 = pxg * 9;

  double acc[4][8];
#pragma unroll
  for (int k = 0; k < 4; ++k)
#pragma unroll
    for (int p = 0; p < 8; ++p) acc[k][p] = 0.0;

  for (int i = tid; i < 3 * 198; i += 256) {
    int ci = i / 198;
    int rem = i - ci * 198;
    int r = rem / 66;
    int px = rem - r * 66;
    int yy = y + r - 1;
    int xx = x0base + px - 1;
    float v = 0.f;
    if (yy >= 0 && yy < HH && xx >= 0 && xx < WW)
      v = in[((b * 3 + ci) * HH + yy) * WW + xx];
    s_in[ci][r][px + (px >> 3)] = (double)v;
  }
  for (int i = tid; i < 128 * 27; i += 256) {
    int oc = i / 27;
    int j = i - oc * 27;
    s_w[j][oc] = w[oc * 27 + j];
  }
  __syncthreads();
#pragma unroll 1
  for (int ci = 0; ci < 3; ++ci) {
#pragma unroll
    for (int r = 0; r < 3; ++r) {
      double ind[10];
#pragma unroll
      for (int m = 0; m < 8; ++m) ind[m] = s_in[ci][r][f0 + m];
      ind[8] = s_in[ci][r][f0 + 9];
      ind[9] = s_in[ci][r][f0 + 10];
#pragma unroll
      for (int dx = 0; dx < 3; ++dx) {
        float4 w4 = *reinterpret_cast<const float4*>(&s_w[ci * 9 + r * 3 + dx][ocg * 4]);
        double wd[4] = {(double)w4.x, (double)w4.y, (double)w4.z, (double)w4.w};
#pragma unroll
        for (int k = 0; k < 4; ++k)
#pragma unroll
          for (int p = 0; p < 8; ++p) acc[k][p] += wd[k] * ind[p + dx];
      }
    }
  }
#pragma unroll
  for (int k = 0; k < 4; ++k) {
    int oc = ocg * 4 + k;
    double bv = (double)bias[oc];
    float* op = out + ((b * 128 + oc) * HH + y) * WW + x0base + x0;
    float4 v = {(float)(acc[k][0] + bv), (float)(acc[k][1] + bv),
                (float)(acc[k][2] + bv), (float)(acc[k][3] + bv)};
    float4 v2 = {(float)(acc[k][4] + bv), (float)(acc[k][5] + bv),
                 (float)(acc[k][6] + bv), (float)(acc[k][7] + bv)};
    *reinterpret_cast<float4*>(op) = v;
    *reinterpret_cast<float4*>(op + 4) = v2;
  }
}

// ---------- 1x1 conv (pre-VQ), fp32 chain acc (r14-proven) ----------
__global__ __launch_bounds__(256, 3) void prevq_nhwc(
    const float* __restrict__ in, const float* __restrict__ wmat,
    const float* __restrict__ bias, float* __restrict__ flat) {
  __shared__ __align__(16) float s_z[32][68];
  __shared__ __align__(16) float s_w[32][132];
  const int tid = threadIdx.x;
  const int b = blockIdx.x >> 8;
  const int y = (blockIdx.x >> 1) & 127;
  const int x0base = (blockIdx.x & 1) << 6;
  const int ocg = tid >> 3;
  const int pxg = tid & 7;
  float acc[4][8];
#pragma unroll
  for (int k = 0; k < 4; ++k)
#pragma unroll
    for (int p = 0; p < 8; ++p) acc[k][p] = 0.f;

#pragma unroll 1
  for (int c0 = 0; c0 < 128; c0 += 32) {
    for (int t = tid; t < 32 * 64; t += 256) {
      int c = t >> 6, px = t & 63;
      s_z[c][px] = in[((b * 128 + c0 + c) * HH + y) * WW + x0base + px];
    }
    for (int t = tid; t < 32 * 128; t += 256) {
      int o = t >> 5, c = t & 31;
      s_w[c][o] = wmat[o * 128 + c0 + c];
    }
    __syncthreads();
#pragma unroll 1
    for (int c = 0; c < 32; ++c) {
      float f8[8];
#pragma unroll
      for (int p = 0; p < 8; ++p) f8[p] = s_z[c][pxg * 8 + p];
      float4 w4 = *reinterpret_cast<const float4*>(&s_w[c][ocg * 4]);
      float wd[4] = {w4.x, w4.y, w4.z, w4.w};
#pragma unroll
      for (int k = 0; k < 4; ++k)
#pragma unroll
        for (int p = 0; p < 8; ++p) acc[k][p] = __fmaf_rn(wd[k], f8[p], acc[k][p]);
    }
    __syncthreads();
  }
  float bv[4];
#pragma unroll
  for (int k = 0; k < 4; ++k) bv[k] = bias[ocg * 4 + k];
  const int pixbase = (b * HH + y) * WW + x0base + pxg * 8;
#pragma unroll
  for (int p = 0; p < 8; ++p) {
    float* op = flat + (pixbase + p) * DD + ocg * 4;
#pragma unroll
    for (int k = 0; k < 4; ++k) op[k] = __fadd_rn(acc[k][p], bv[k]);
  }
}

// ---------- numpy-faithful fp32 sum of squares over 128 elems ----------
__device__ __forceinline__ float pairwise8_sq(const float* v) {
  float r[8];
#pragma unroll
  for (int j = 0; j < 8; ++j) r[j] = __fmul_rn(v[j], v[j]);
#pragma unroll
  for (int i = 8; i < 128; i += 8)
#pragma unroll
    for (int j = 0; j < 8; ++j) r[j] = __fadd_rn(r[j], __fmul_rn(v[i + j], v[i + j]));
  return __fadd_rn(__fadd_rn(__fadd_rn(r[0], r[1]), __fadd_rn(r[2], r[3])),
                   __fadd_rn(__fadd_rn(r[4], r[5]), __fadd_rn(r[6], r[7])));
}

// ---------- fused VQ, reference-faithful fp32 scoring (DO NOT CHANGE MATH) ----------
constexpr int SF_OFF = 0;
constexpr int SC_OFF = 33792;
constexpr int SRB_OFF = SC_OFF;
constexpr int SRI_OFF = SC_OFF + 4352;
constexpr int SCN_OFF = SC_OFF + 33792;
constexpr int SZN_OFF = SCN_OFF + 256;
constexpr int SIDX_OFF = SZN_OFF + 256;
constexpr int SRED_OFF = SIDX_OFF + 256;
constexpr int SMEM_BYTES = SRED_OFF + 32;

__global__ __launch_bounds__(256, 2) void vq_fused(
    const float* __restrict__ flat, const float* __restrict__ codebook,
    ushort* __restrict__ q16, float* __restrict__ partial, int* __restrict__ counts) {
  __shared__ __align__(16) char smem[SMEM_BYTES];
  float (*s_f)[132] = reinterpret_cast<float (*)[132]>(smem + SF_OFF);
  float (*s_c)[132] = reinterpret_cast<float (*)[132]>(smem + SC_OFF);
  float (*s_rb)[4][17] = reinterpret_cast<float (*)[4][17]>(smem + SRB_OFF);
  int (*s_ri)[4][17] = reinterpret_cast<int (*)[4][17]>(smem + SRI_OFF);
  float* s_cn = reinterpret_cast<float*>(smem + SCN_OFF);
  float* s_zn = reinterpret_cast<float*>(smem + SZN_OFF);
  int* s_idx = reinterpret_cast<int*>(smem + SIDX_OFF);
  double* s_red = reinterpret_cast<double*>(smem + SRED_OFF);

  const int tid = threadIdx.x;
  const int n0 = blockIdx.x * VQ_BLK_PX;
  const int pxg = tid & 15;
  const int cg = tid >> 4;

  for (int t = tid; t < VQ_BLK_PX * 128; t += 256) {
    int i = t >> 7, d = t & 127;
    s_f[i][d] = flat[(n0 + i) * DD + d];
  }
  __syncthreads();
  if (tid < VQ_BLK_PX) s_zn[tid] = pairwise8_sq(&s_f[tid][0]);

  float best[4] = {3.402823466e+38f, 3.402823466e+38f,
                   3.402823466e+38f, 3.402823466e+38f};
  int bi[4] = {0, 0, 0, 0};

#pragma unroll 1
  for (int c0 = 0; c0 < KK; c0 += 64) {
    for (int t = tid; t < 64 * 128; t += 256) {
      int cc = t >> 7, d = t & 127;
      s_c[cc][d] = codebook[(c0 + cc) * DD + d];
    }
    __syncthreads();
    if (tid < 64) s_cn[tid] = pairwise8_sq(&s_c[tid][0]);
    __syncthreads();
    float acc[4][4];
#pragma unroll
    for (int i = 0; i < 4; ++i)
#pragma unroll
      for (int j = 0; j < 4; ++j) acc[i][j] = 0.f;
#pragma unroll 1
    for (int d0 = 0; d0 < 128; d0 += 4) {
      float4 f4[4], c4[4];
#pragma unroll
      for (int i = 0; i < 4; ++i)
        f4[i] = *reinterpret_cast<const float4*>(&s_f[pxg * 4 + i][d0]);
#pragma unroll
      for (int j = 0; j < 4; ++j)
        c4[j] = *reinterpret_cast<const float4*>(&s_c[cg * 4 + j][d0]);
#pragma unroll
      for (int i = 0; i < 4; ++i) {
#pragma unroll
        for (int j = 0; j < 4; ++j) {
          acc[i][j] = __fmaf_rn(f4[i].x, c4[j].x, acc[i][j]);
          acc[i][j] = __fmaf_rn(f4[i].y, c4[j].y, acc[i][j]);
          acc[i][j] = __fmaf_rn(f4[i].z, c4[j].z, acc[i][j]);
          acc[i][j] = __fmaf_rn(f4[i].w, c4[j].w, acc[i][j]);
        }
      }
    }
#pragma unroll
    for (int i = 0; i < 4; ++i)
#pragma unroll
      for (int j = 0; j < 4; ++j) {
        float score = __fsub_rn(__fadd_rn(s_zn[pxg * 4 + i], s_cn[cg * 4 + j]),
                                __fmul_rn(2.0f, acc[i][j]));
        int code = c0 + cg * 4 + j;
        if (score < best[i]) { best[i] = score; bi[i] = code; }
      }
    __syncthreads();
  }
#pragma unroll
  for (int i = 0; i < 4; ++i) {
    s_rb[pxg][i][cg] = best[i];
    s_ri[pxg][i][cg] = bi[i];
  }
  __syncthreads();
  if (tid < 16) {
    for (int i = 0; i < 4; ++i) {
      float m = s_rb[tid][i][0];
      int mi = s_ri[tid][i][0];
      for (int g = 1; g < 16; ++g) {
        float v = s_rb[tid][i][g];
        int vi = s_ri[tid][i][g];
        if (v < m || (v == m && vi < mi)) { m = v; mi = vi; }
      }
      s_idx[tid * 4 + i] = mi;
    }
  }
  __syncthreads();
  if (tid < VQ_BLK_PX) atomicAdd(&counts[s_idx[tid]], 1);

  // gather -> q (bf16 NHWC) + fp64 SSE vs fp32 z (still in s_f)
  const int px = tid & 63;
  const int dg = tid >> 6;
  const int n = n0 + px;
  const int k = s_idx[px];
  const float* crow = codebook + k * DD + dg * 32;
  ushort* qb = q16 + (size_t)n * 128 + dg * 32;
  double s = 0.0;
#pragma unroll 4
  for (int j = 0; j < 32; ++j) {
    float e = crow[j];
    double dd = (double)e - (double)s_f[px][dg * 32 + j];
    s += dd * dd;
    qb[j] = f2bf(e);
  }
  for (int off = 32; off; off >>= 1) s += __shfl_down(s, off);
  if ((tid & 63) == 0) s_red[tid >> 6] = s;
  __syncthreads();
  if (tid == 0)
    partial[blockIdx.x] = (float)(s_red[0] + s_red[1] + s_red[2] + s_red[3]);
}

// ---------- decoder 3x3 conv via bf16 MFMA (r15-proven, unchanged) ----------
template <bool LAST>
__global__ __launch_bounds__(256, 4) void dec_mfma(
    const ushort* __restrict__ inq, const ushort* __restrict__ wb,
    const float* __restrict__ bias, float* __restrict__ outf,
    ushort* __restrict__ outq) {
  const int b = blockIdx.x >> 7;
  const int y = blockIdx.x & 127;
  const int lane = threadIdx.x & 63;
  const int wv = threadIdx.x >> 6;
  const int oc0 = wv << 5;
  const int lrow = lane & 15;
  const int lk = lane >> 4;

  f32x4 acc[8][2];
#pragma unroll
  for (int mt = 0; mt < 8; ++mt)
#pragma unroll
    for (int nt = 0; nt < 2; ++nt) acc[mt][nt] = (f32x4){0.f, 0.f, 0.f, 0.f};

#pragma unroll 1
  for (int tap = 0; tap < 9; ++tap) {
    const int ky = tap / 3, kx = tap % 3;
    const int yy = y + ky - 1;
    const bool yok = (yy >= 0) && (yy < HH);
    const ushort* wtap = wb + tap * (16 * 128 * 8);
    const ushort* rowp = inq + ((size_t)(b * HH + yy) * WW) * 128;
#pragma unroll 1
    for (int cb = 0; cb < 4; ++cb) {
      const int cib = cb * 4 + lk;
      bf16x8 bfr0 = *reinterpret_cast<const bf16x8*>(wtap + ((size_t)(cib * 128) + oc0 + lrow) * 8);
      bf16x8 bfr1 = *reinterpret_cast<const bf16x8*>(wtap + ((size_t)(cib * 128) + oc0 + 16 + lrow) * 8);
#pragma unroll
      for (int mt = 0; mt < 8; ++mt) {
        const int xx = mt * 16 + lrow + kx - 1;
        bf16x8 af = {0, 0, 0, 0, 0, 0, 0, 0};
        if (yok && xx >= 0 && xx < WW)
          af = *reinterpret_cast<const bf16x8*>(rowp + (size_t)xx * 128 + cib * 8);
        acc[mt][0] = __builtin_amdgcn_mfma_f32_16x16x32_bf16(af, bfr0, acc[mt][0], 0, 0, 0);
        acc[mt][1] = __builtin_amdgcn_mfma_f32_16x16x32_bf16(af, bfr1, acc[mt][1], 0, 0, 0);
      }
    }
  }
#pragma unroll
  for (int nt = 0; nt < 2; ++nt) {
    const int oc = oc0 + nt * 16 + lrow;
    const float bv = bias[oc];
    if constexpr (LAST) {
#pragma unroll
      for (int mt = 0; mt < 8; ++mt) {
        const int px = mt * 16 + lk * 4;
        float4 v = {acc[mt][nt][0] + bv, acc[mt][nt][1] + bv,
                    acc[mt][nt][2] + bv, acc[mt][nt][3] + bv};
        *reinterpret_cast<float4*>(outf + ((size_t)(b * 128 + oc) * HH + y) * WW + px) = v;
      }
    } else {
#pragma unroll
      for (int mt = 0; mt < 8; ++mt) {
#pragma unroll
        for (int m = 0; m < 4; ++m) {
          const int px = mt * 16 + lk * 4 + m;
          outq[((size_t)(b * HH + y) * WW + px) * 128 + oc] = f2bf(acc[mt][nt][m] + bv);
        }
      }
    }
  }
}

// ---------- final conv-transpose 128 -> 3: 2-row blocks, 256 threads ----------
// Same per-output FMA chain (ci0 -> ci -> r -> dx -> oc) as before.
__global__ __launch_bounds__(256, 3) void conv_out3(
    const float* __restrict__ in, const float* __restrict__ w,
    const float* __restrict__ bias, float* __restrict__ out) {
  __shared__ float s_in[16][4][130];  // [ci][row window y0-1..y0+2][px=x+1]
  __shared__ float s_w[128][28];      // [ci][tap*3+oc]
  const int tid = threadIdx.x;
  const int b = blockIdx.x >> 6;
  const int y0 = (blockIdx.x & 63) << 1;
  const int yloc = tid >> 7;  // 0 or 1
  const int x = tid & 127;
  const int y = y0 + yloc;
  for (int i = tid; i < 128 * 27; i += 256) {
    int ci = i / 27, rem = i % 27, oc = rem / 9, tap = rem % 9;
    int ky = tap / 3, kx = tap % 3;
    s_w[ci][tap * 3 + oc] = w[((ci * 3 + oc) * 3 + (2 - ky)) * 3 + (2 - kx)];
  }
  float acc[3] = {0.f, 0.f, 0.f};
#pragma unroll 1
  for (int ci0 = 0; ci0 < 128; ci0 += 16) {
    for (int i = tid; i < 16 * 520; i += 256) {
      int ci = i / 520;
      int rem = i - ci * 520;
      int r = rem / 130;
      int px = rem - r * 130;
      int yy = y0 + r - 1;
      float v = 0.f;
      if (yy >= 0 && yy < HH && px >= 1 && px <= 128)
        v = in[((b * 128 + ci0 + ci) * HH + yy) * WW + (px - 1)];
      s_in[ci][r][px] = v;
    }
    __syncthreads();
#pragma unroll 1
    for (int ci = 0; ci < 16; ++ci) {
#pragma unroll
      for (int r = 0; r < 3; ++r) {
        float i3[3] = {s_in[ci][yloc + r][x], s_in[ci][yloc + r][x + 1],
                       s_in[ci][yloc + r][x + 2]};
#pragma unroll
        for (int dx = 0; dx < 3; ++dx)
#pragma unroll
          for (int oc = 0; oc < 3; ++oc)
            acc[oc] += s_w[ci0 + ci][(r * 3 + dx) * 3 + oc] * i3[dx];
      }
    }
    __syncthreads();
  }
#pragma unroll
  for (int oc = 0; oc < 3; ++oc)
    out[((b * 3 + oc) * HH + y) * WW + x] = acc[oc] + bias[oc];
}

// ---------- finalize: loss + perplexity (fp64; runs before decoder) ----------
__global__ void finalize(const float* __restrict__ partial,
                         const int* __restrict__ counts, float* __restrict__ out) {
  __shared__ double redh[4], reds[4];
  const int tid = threadIdx.x;
  double h = 0.0;
  for (int k = tid; k < KK; k += 256) {
    double p = (double)counts[k] * (1.0 / (double)NPIX);
    h += p * log(p + 1e-10);
  }
  double s = 0.0;
  for (int i = tid; i < VQ_BLOCKS; i += 256) s += (double)partial[i];
  for (int off = 32; off; off >>= 1) {
    h += __shfl_down(h, off);
    s += __shfl_down(s, off);
  }
  if ((tid & 63) == 0) { redh[tid >> 6] = h; reds[tid >> 6] = s; }
  __syncthreads();
  if (tid == 0) {
    double Hs = redh[0] + redh[1] + redh[2] + redh[3];
    double Ss = reds[0] + reds[1] + reds[2] + reds[3];
    out[0] = (float)(0.25 * Ss * (1.0 / (double)NELEM));
    out[1 + XRECON] = (float)exp(-Hs);
  }
}

}  // namespace

extern "C" void kernel_launch(void* const* d_in, const int* in_sizes, int n_in,
                              void* d_out, int out_size, void* d_ws, size_t ws_size,
                              hipStream_t stream) {
  (void)in_sizes; (void)n_in; (void)out_size; (void)ws_size;
  const float* x       = (const float*)d_in[0];
  const float* enc_w0  = (const float*)d_in[1];
  const float* enc_b0  = (const float*)d_in[2];
  const float* enc_wh  = (const float*)d_in[3];
  const float* enc_bh  = (const float*)d_in[4];
  const float* pre_w   = (const float*)d_in[5];
  const float* pre_b   = (const float*)d_in[6];
  const float* codebook= (const float*)d_in[7];
  const float* dec_wh  = (const float*)d_in[8];
  const float* dec_bh  = (const float*)d_in[9];
  const float* dec_wl  = (const float*)d_in[10];
  const float* dec_bl  = (const float*)d_in[11];
  float* out = (float*)d_out;

  // Workspace: A, Bf = two NELEM fp32 buffers (256 MiB total).
  // Bf is reinterpreted as two bf16 NHWC buffers (Q0, Q1) for the decoder.
  float* A = (float*)d_ws;
  float* Bf = A + NELEM;
  ushort* Q0 = (ushort*)Bf;
  ushort* Q1 = Q0 + NELEM;

  // Transient scratch in d_out's x_recon region (all consumed before
  // conv_out3 overwrites it): counts, partial, enc fp32 wbuf, 3x dec bf16.
  int* counts = (int*)(out + 1);
  float* partial = out + 1 + KK;
  float* wbuf = out + 4612;
  ushort* wb0 = (ushort*)(wbuf + 147456);
  ushort* wb1 = wb0 + 147456;
  ushort* wb2 = wb1 + 147456;

  const int LSTRIDE = 128 * 128 * 9;
  const int RGRID = NB * HH;       // 2048
  const int CGRID = NB * HH * 2;   // 4096
  const int WGRID = 576;           // 147456 / 256

  zero_counts<<<1, 256, 0, stream>>>(counts);

  // encoder: layer-1 fp64; 128-convs fp32 chain acc via scalar-weight conv
  conv_l1<<<CGRID, 256, 0, stream>>>(x, enc_w0, enc_b0, A);
  repack_w<<<WGRID, 256, 0, stream>>>(enc_wh, wbuf);
  conv3x3_s<8><<<RGRID, 256, 0, stream>>>(A, wbuf, enc_bh, Bf);
  repack_w<<<WGRID, 256, 0, stream>>>(enc_wh + LSTRIDE, wbuf);
  conv3x3_s<8><<<RGRID, 256, 0, stream>>>(Bf, wbuf, enc_bh + 128, A);
  repack_w<<<WGRID, 256, 0, stream>>>(enc_wh + 2 * LSTRIDE, wbuf);
  conv3x3_s<8><<<RGRID, 256, 0, stream>>>(A, wbuf, enc_bh + 256, Bf);

  // pre-VQ 1x1 -> fp32 NHWC flat in A
  prevq_nhwc<<<CGRID, 256, 0, stream>>>(Bf, pre_w, pre_b, A);

  // decoder weight repacks (bf16, TRANS flip folded in)
  repack_wb16<<<WGRID, 256, 0, stream>>>(dec_wh, wb0);
  repack_wb16<<<WGRID, 256, 0, stream>>>(dec_wh + LSTRIDE, wb1);
  repack_wb16<<<WGRID, 256, 0, stream>>>(dec_wh + 2 * LSTRIDE, wb2);

  // VQ: fp32 BLAS-order scores (locked since r7); q -> Q0 (bf16 NHWC)
  vq_fused<<<VQ_BLOCKS, 256, 0, stream>>>(A, codebook, Q0, partial, counts);

  // loss + perplexity (before decoder/conv_out3 overwrite the scratch)
  finalize<<<1, 256, 0, stream>>>(partial, counts, out);

  // decoder: bf16 MFMA convs (fp32 accumulate); last emits fp32 NCHW into A
  dec_mfma<false><<<RGRID, 256, 0, stream>>>(Q0, wb0, dec_bh, nullptr, Q1);
  dec_mfma<false><<<RGRID, 256, 0, stream>>>(Q1, wb1, dec_bh + 128, nullptr, Q0);
  dec_mfma<true><<<RGRID, 256, 0, stream>>>(Q0, wb2, dec_bh + 256, A, nullptr);
  conv_out3<<<NB * HH / 2, 256, 0, stream>>>(A, dec_wl, dec_bl, out + 1);
}

// Round 17
// 4737.642 us; speedup vs baseline: 1.1454x; 1.1454x over previous
//
#include <hip/hip_runtime.h>

namespace {

constexpr int NB = 16, HH = 128, WW = 128, KK = 512, DD = 128;
constexpr int NPIX = NB * HH * WW;        // 262144
constexpr int NELEM = NPIX * DD;          // 33554432
constexpr int XRECON = NB * 3 * HH * WW;  // 786432
constexpr int VQ_BLK_PX = 64;
constexpr int VQ_BLOCKS = NPIX / VQ_BLK_PX;  // 4096

using bf16x8 = __attribute__((ext_vector_type(8))) short;
using f32x4 = __attribute__((ext_vector_type(4))) float;

__device__ __forceinline__ ushort f2bf(float f) {
  unsigned u = __float_as_uint(f);
  return (ushort)((u + 0x7FFFu + ((u >> 16) & 1u)) >> 16);  // RNE
}

// ---------- zero the code-usage histogram (lives in d_out scratch) ----------
__global__ void zero_counts(int* __restrict__ counts) {
  const int t = threadIdx.x;
  counts[t] = 0;
  counts[t + 256] = 0;
}

// swizzle preserving 8B alignment at even px: phys = px + (px>>5)*4
__device__ __forceinline__ int swz(int px) { return px + ((px >> 5) << 2); }

// ---------- fp32 weight repack: w -> wr[ci][tap][oc] (encoder) ----------
__global__ void repack_w(const float* __restrict__ w, float* __restrict__ wr) {
  int i = blockIdx.x * 256 + threadIdx.x;  // over 128*9*128
  int oc = i & 127;
  int tap = (i >> 7) % 9;
  int ci = i / (9 * 128);
  wr[i] = w[(oc * 128 + ci) * 9 + tap];
}

// ---------- bf16 weight repack (decoder, TRANS flip): wr[tap][ci/8][oc][8] ----------
__global__ void repack_wb16(const float* __restrict__ w, ushort* __restrict__ wr) {
  int i = blockIdx.x * 256 + threadIdx.x;  // 9*16*128*8 = 147456
  int j = i & 7;
  int oc = (i >> 3) & 127;
  int cib = (i >> 10) & 15;
  int tap = i >> 14;
  int ci = cib * 8 + j;
  int ky = tap / 3, kx = tap % 3;
  float v = w[((size_t)ci * 128 + oc) * 9 + (2 - ky) * 3 + (2 - kx)];
  wr[i] = f2bf(v);
}

// ---------- 3x3 conv 128->128 fp32, scalar-weight path (encoder) ----------
// CT=16 (r15-proven), bounds(256,5): +1 block/CU vs r15, barriers unchanged.
// Per-output FMA chain ci->r->dx ascending: BIT-IDENTICAL to r9-r16.
template <int CT>
__global__ __launch_bounds__(256, 5) void conv3x3_s(
    const float* __restrict__ in, const float* __restrict__ wr,
    const float* __restrict__ bias, float* __restrict__ out) {
  __shared__ __align__(16) float s_in[CT][3][148];
  const int tid = threadIdx.x;
  const int b = blockIdx.x >> 7;
  const int y = blockIdx.x & 127;
  const int lane = tid & 63;
  const int wv = __builtin_amdgcn_readfirstlane(tid >> 6);
  const int oc0 = wv << 5;
  const int px0 = lane << 1;

  float acc[32][2];
#pragma unroll
  for (int k = 0; k < 32; ++k) { acc[k][0] = 0.f; acc[k][1] = 0.f; }

  const int f_lo = swz(px0);
  const int f_hi = swz(px0 + 2);

#pragma unroll 1
  for (int ci0 = 0; ci0 < 128; ci0 += CT) {
    for (int i = tid; i < CT * 390; i += 256) {
      int ci = i / 390;
      int rem = i - ci * 390;
      int r = rem / 130;
      int px = rem - r * 130;
      int yy = y + r - 1;
      int xx = px - 1;
      float v = 0.f;
      if (yy >= 0 && yy < HH && xx >= 0 && xx < WW)
        v = in[((b * 128 + ci0 + ci) * HH + yy) * WW + xx];
      s_in[ci][r][swz(px)] = v;
    }
    __syncthreads();
#pragma unroll 1
    for (int ci = 0; ci < CT; ++ci) {
      float ind[3][4];
#pragma unroll
      for (int r = 0; r < 3; ++r) {
        float2 a = *reinterpret_cast<const float2*>(&s_in[ci][r][f_lo]);
        float2 c = *reinterpret_cast<const float2*>(&s_in[ci][r][f_hi]);
        ind[r][0] = a.x; ind[r][1] = a.y; ind[r][2] = c.x; ind[r][3] = c.y;
      }
      const float* wp = wr + (size_t)(ci0 + ci) * 9 * 128 + oc0;
#pragma unroll
      for (int r = 0; r < 3; ++r) {
#pragma unroll
        for (int dx = 0; dx < 3; ++dx) {
          const float* wt = wp + (r * 3 + dx) * 128;
          float ws[32];
#pragma unroll
          for (int k = 0; k < 32; ++k) ws[k] = wt[k];
          float v0 = ind[r][dx], v1 = ind[r][dx + 1];
#pragma unroll
          for (int k = 0; k < 32; ++k) {
            acc[k][0] = __fmaf_rn(ws[k], v0, acc[k][0]);
            acc[k][1] = __fmaf_rn(ws[k], v1, acc[k][1]);
          }
        }
      }
    }
    __syncthreads();
  }
#pragma unroll
  for (int k = 0; k < 32; ++k) {
    int oc = oc0 + k;
    float bv = bias[oc];
    float2 v = {acc[k][0] + bv, acc[k][1] + bv};
    *reinterpret_cast<float2*>(out + ((b * 128 + oc) * HH + y) * WW + px0) = v;
  }
}

// ---------- layer-1 conv 3->128, fp64 acc (r14-proven, spill-free) ----------
__global__ __launch_bounds__(256, 3) void conv_l1(
    const float* __restrict__ in, const float* __restrict__ w,
    const float* __restrict__ bias, float* __restrict__ out) {
  __shared__ __align__(16) double s_in[3][3][74];
  __shared__ __align__(16) float s_w[27][132];
  const int tid = threadIdx.x;
  const int b = blockIdx.x >> 8;
  const int y = (blockIdx.x >> 1) & 127;
  const int x0base = (blockIdx.x & 1) << 6;
  const int ocg = tid >> 3;
  const int pxg = tid & 7;
  const int x0 = pxg * 8;
  const int f0 = pxg * 9;

  double acc[4][8];
#pragma unroll
  for (int k = 0; k < 4; ++k)
#pragma unroll
    for (int p = 0; p < 8; ++p) acc[k][p] = 0.0;

  for (int i = tid; i < 3 * 198; i += 256) {
    int ci = i / 198;
    int rem = i - ci * 198;
    int r = rem / 66;
    int px = rem - r * 66;
    int yy = y + r - 1;
    int xx = x0base + px - 1;
    float v = 0.f;
    if (yy >= 0 && yy < HH && xx >= 0 && xx < WW)
      v = in[((b * 3 + ci) * HH + yy) * WW + xx];
    s_in[ci][r][px + (px >> 3)] = (double)v;
  }
  for (int i = tid; i < 128 * 27; i += 256) {
    int oc = i / 27;
    int j = i - oc * 27;
    s_w[j][oc] = w[oc * 27 + j];
  }
  __syncthreads();
#pragma unroll 1
  for (int ci = 0; ci < 3; ++ci) {
#pragma unroll
    for (int r = 0; r < 3; ++r) {
      double ind[10];
#pragma unroll
      for (int m = 0; m < 8; ++m) ind[m] = s_in[ci][r][f0 + m];
      ind[8] = s_in[ci][r][f0 + 9];
      ind[9] = s_in[ci][r][f0 + 10];
#pragma unroll
      for (int dx = 0; dx < 3; ++dx) {
        float4 w4 = *reinterpret_cast<const float4*>(&s_w[ci * 9 + r * 3 + dx][ocg * 4]);
        double wd[4] = {(double)w4.x, (double)w4.y, (double)w4.z, (double)w4.w};
#pragma unroll
        for (int k = 0; k < 4; ++k)
#pragma unroll
          for (int p = 0; p < 8; ++p) acc[k][p] += wd[k] * ind[p + dx];
      }
    }
  }
#pragma unroll
  for (int k = 0; k < 4; ++k) {
    int oc = ocg * 4 + k;
    double bv = (double)bias[oc];
    float* op = out + ((b * 128 + oc) * HH + y) * WW + x0base + x0;
    float4 v = {(float)(acc[k][0] + bv), (float)(acc[k][1] + bv),
                (float)(acc[k][2] + bv), (float)(acc[k][3] + bv)};
    float4 v2 = {(float)(acc[k][4] + bv), (float)(acc[k][5] + bv),
                 (float)(acc[k][6] + bv), (float)(acc[k][7] + bv)};
    *reinterpret_cast<float4*>(op) = v;
    *reinterpret_cast<float4*>(op + 4) = v2;
  }
}

// ---------- 1x1 conv (pre-VQ), fp32 chain acc (r14-proven) ----------
__global__ __launch_bounds__(256, 3) void prevq_nhwc(
    const float* __restrict__ in, const float* __restrict__ wmat,
    const float* __restrict__ bias, float* __restrict__ flat) {
  __shared__ __align__(16) float s_z[32][68];
  __shared__ __align__(16) float s_w[32][132];
  const int tid = threadIdx.x;
  const int b = blockIdx.x >> 8;
  const int y = (blockIdx.x >> 1) & 127;
  const int x0base = (blockIdx.x & 1) << 6;
  const int ocg = tid >> 3;
  const int pxg = tid & 7;
  float acc[4][8];
#pragma unroll
  for (int k = 0; k < 4; ++k)
#pragma unroll
    for (int p = 0; p < 8; ++p) acc[k][p] = 0.f;

#pragma unroll 1
  for (int c0 = 0; c0 < 128; c0 += 32) {
    for (int t = tid; t < 32 * 64; t += 256) {
      int c = t >> 6, px = t & 63;
      s_z[c][px] = in[((b * 128 + c0 + c) * HH + y) * WW + x0base + px];
    }
    for (int t = tid; t < 32 * 128; t += 256) {
      int o = t >> 5, c = t & 31;
      s_w[c][o] = wmat[o * 128 + c0 + c];
    }
    __syncthreads();
#pragma unroll 1
    for (int c = 0; c < 32; ++c) {
      float f8[8];
#pragma unroll
      for (int p = 0; p < 8; ++p) f8[p] = s_z[c][pxg * 8 + p];
      float4 w4 = *reinterpret_cast<const float4*>(&s_w[c][ocg * 4]);
      float wd[4] = {w4.x, w4.y, w4.z, w4.w};
#pragma unroll
      for (int k = 0; k < 4; ++k)
#pragma unroll
        for (int p = 0; p < 8; ++p) acc[k][p] = __fmaf_rn(wd[k], f8[p], acc[k][p]);
    }
    __syncthreads();
  }
  float bv[4];
#pragma unroll
  for (int k = 0; k < 4; ++k) bv[k] = bias[ocg * 4 + k];
  const int pixbase = (b * HH + y) * WW + x0base + pxg * 8;
#pragma unroll
  for (int p = 0; p < 8; ++p) {
    float* op = flat + (pixbase + p) * DD + ocg * 4;
#pragma unroll
    for (int k = 0; k < 4; ++k) op[k] = __fadd_rn(acc[k][p], bv[k]);
  }
}

// ---------- numpy-faithful fp32 sum of squares over 128 elems ----------
__device__ __forceinline__ float pairwise8_sq(const float* v) {
  float r[8];
#pragma unroll
  for (int j = 0; j < 8; ++j) r[j] = __fmul_rn(v[j], v[j]);
#pragma unroll
  for (int i = 8; i < 128; i += 8)
#pragma unroll
    for (int j = 0; j < 8; ++j) r[j] = __fadd_rn(r[j], __fmul_rn(v[i + j], v[i + j]));
  return __fadd_rn(__fadd_rn(__fadd_rn(r[0], r[1]), __fadd_rn(r[2], r[3])),
                   __fadd_rn(__fadd_rn(r[4], r[5]), __fadd_rn(r[6], r[7])));
}

// ---------- fused VQ, reference-faithful fp32 scoring (DO NOT CHANGE MATH) ----------
constexpr int SF_OFF = 0;
constexpr int SC_OFF = 33792;
constexpr int SRB_OFF = SC_OFF;
constexpr int SRI_OFF = SC_OFF + 4352;
constexpr int SCN_OFF = SC_OFF + 33792;
constexpr int SZN_OFF = SCN_OFF + 256;
constexpr int SIDX_OFF = SZN_OFF + 256;
constexpr int SRED_OFF = SIDX_OFF + 256;
constexpr int SMEM_BYTES = SRED_OFF + 32;

__global__ __launch_bounds__(256, 2) void vq_fused(
    const float* __restrict__ flat, const float* __restrict__ codebook,
    ushort* __restrict__ q16, float* __restrict__ partial, int* __restrict__ counts) {
  __shared__ __align__(16) char smem[SMEM_BYTES];
  float (*s_f)[132] = reinterpret_cast<float (*)[132]>(smem + SF_OFF);
  float (*s_c)[132] = reinterpret_cast<float (*)[132]>(smem + SC_OFF);
  float (*s_rb)[4][17] = reinterpret_cast<float (*)[4][17]>(smem + SRB_OFF);
  int (*s_ri)[4][17] = reinterpret_cast<int (*)[4][17]>(smem + SRI_OFF);
  float* s_cn = reinterpret_cast<float*>(smem + SCN_OFF);
  float* s_zn = reinterpret_cast<float*>(smem + SZN_OFF);
  int* s_idx = reinterpret_cast<int*>(smem + SIDX_OFF);
  double* s_red = reinterpret_cast<double*>(smem + SRED_OFF);

  const int tid = threadIdx.x;
  const int n0 = blockIdx.x * VQ_BLK_PX;
  const int pxg = tid & 15;
  const int cg = tid >> 4;

  for (int t = tid; t < VQ_BLK_PX * 128; t += 256) {
    int i = t >> 7, d = t & 127;
    s_f[i][d] = flat[(n0 + i) * DD + d];
  }
  __syncthreads();
  if (tid < VQ_BLK_PX) s_zn[tid] = pairwise8_sq(&s_f[tid][0]);

  float best[4] = {3.402823466e+38f, 3.402823466e+38f,
                   3.402823466e+38f, 3.402823466e+38f};
  int bi[4] = {0, 0, 0, 0};

#pragma unroll 1
  for (int c0 = 0; c0 < KK; c0 += 64) {
    for (int t = tid; t < 64 * 128; t += 256) {
      int cc = t >> 7, d = t & 127;
      s_c[cc][d] = codebook[(c0 + cc) * DD + d];
    }
    __syncthreads();
    if (tid < 64) s_cn[tid] = pairwise8_sq(&s_c[tid][0]);
    __syncthreads();
    float acc[4][4];
#pragma unroll
    for (int i = 0; i < 4; ++i)
#pragma unroll
      for (int j = 0; j < 4; ++j) acc[i][j] = 0.f;
#pragma unroll 1
    for (int d0 = 0; d0 < 128; d0 += 4) {
      float4 f4[4], c4[4];
#pragma unroll
      for (int i = 0; i < 4; ++i)
        f4[i] = *reinterpret_cast<const float4*>(&s_f[pxg * 4 + i][d0]);
#pragma unroll
      for (int j = 0; j < 4; ++j)
        c4[j] = *reinterpret_cast<const float4*>(&s_c[cg * 4 + j][d0]);
#pragma unroll
      for (int i = 0; i < 4; ++i) {
#pragma unroll
        for (int j = 0; j < 4; ++j) {
          acc[i][j] = __fmaf_rn(f4[i].x, c4[j].x, acc[i][j]);
          acc[i][j] = __fmaf_rn(f4[i].y, c4[j].y, acc[i][j]);
          acc[i][j] = __fmaf_rn(f4[i].z, c4[j].z, acc[i][j]);
          acc[i][j] = __fmaf_rn(f4[i].w, c4[j].w, acc[i][j]);
        }
      }
    }
#pragma unroll
    for (int i = 0; i < 4; ++i)
#pragma unroll
      for (int j = 0; j < 4; ++j) {
        float score = __fsub_rn(__fadd_rn(s_zn[pxg * 4 + i], s_cn[cg * 4 + j]),
                                __fmul_rn(2.0f, acc[i][j]));
        int code = c0 + cg * 4 + j;
        if (score < best[i]) { best[i] = score; bi[i] = code; }
      }
    __syncthreads();
  }
#pragma unroll
  for (int i = 0; i < 4; ++i) {
    s_rb[pxg][i][cg] = best[i];
    s_ri[pxg][i][cg] = bi[i];
  }
  __syncthreads();
  if (tid < 16) {
    for (int i = 0; i < 4; ++i) {
      float m = s_rb[tid][i][0];
      int mi = s_ri[tid][i][0];
      for (int g = 1; g < 16; ++g) {
        float v = s_rb[tid][i][g];
        int vi = s_ri[tid][i][g];
        if (v < m || (v == m && vi < mi)) { m = v; mi = vi; }
      }
      s_idx[tid * 4 + i] = mi;
    }
  }
  __syncthreads();
  if (tid < VQ_BLK_PX) atomicAdd(&counts[s_idx[tid]], 1);

  // gather -> q (bf16 NHWC) + fp64 SSE vs fp32 z (still in s_f)
  const int px = tid & 63;
  const int dg = tid >> 6;
  const int n = n0 + px;
  const int k = s_idx[px];
  const float* crow = codebook + k * DD + dg * 32;
  ushort* qb = q16 + (size_t)n * 128 + dg * 32;
  double s = 0.0;
#pragma unroll 4
  for (int j = 0; j < 32; ++j) {
    float e = crow[j];
    double dd = (double)e - (double)s_f[px][dg * 32 + j];
    s += dd * dd;
    qb[j] = f2bf(e);
  }
  for (int off = 32; off; off >>= 1) s += __shfl_down(s, off);
  if ((tid & 63) == 0) s_red[tid >> 6] = s;
  __syncthreads();
  if (tid == 0)
    partial[blockIdx.x] = (float)(s_red[0] + s_red[1] + s_red[2] + s_red[3]);
}

// ---------- decoder 3x3 conv via bf16 MFMA (r15-proven, unchanged) ----------
template <bool LAST>
__global__ __launch_bounds__(256, 4) void dec_mfma(
    const ushort* __restrict__ inq, const ushort* __restrict__ wb,
    const float* __restrict__ bias, float* __restrict__ outf,
    ushort* __restrict__ outq) {
  const int b = blockIdx.x >> 7;
  const int y = blockIdx.x & 127;
  const int lane = threadIdx.x & 63;
  const int wv = threadIdx.x >> 6;
  const int oc0 = wv << 5;
  const int lrow = lane & 15;
  const int lk = lane >> 4;

  f32x4 acc[8][2];
#pragma unroll
  for (int mt = 0; mt < 8; ++mt)
#pragma unroll
    for (int nt = 0; nt < 2; ++nt) acc[mt][nt] = (f32x4){0.f, 0.f, 0.f, 0.f};

#pragma unroll 1
  for (int tap = 0; tap < 9; ++tap) {
    const int ky = tap / 3, kx = tap % 3;
    const int yy = y + ky - 1;
    const bool yok = (yy >= 0) && (yy < HH);
    const ushort* wtap = wb + tap * (16 * 128 * 8);
    const ushort* rowp = inq + ((size_t)(b * HH + yy) * WW) * 128;
#pragma unroll 1
    for (int cb = 0; cb < 4; ++cb) {
      const int cib = cb * 4 + lk;
      bf16x8 bfr0 = *reinterpret_cast<const bf16x8*>(wtap + ((size_t)(cib * 128) + oc0 + lrow) * 8);
      bf16x8 bfr1 = *reinterpret_cast<const bf16x8*>(wtap + ((size_t)(cib * 128) + oc0 + 16 + lrow) * 8);
#pragma unroll
      for (int mt = 0; mt < 8; ++mt) {
        const int xx = mt * 16 + lrow + kx - 1;
        bf16x8 af = {0, 0, 0, 0, 0, 0, 0, 0};
        if (yok && xx >= 0 && xx < WW)
          af = *reinterpret_cast<const bf16x8*>(rowp + (size_t)xx * 128 + cib * 8);
        acc[mt][0] = __builtin_amdgcn_mfma_f32_16x16x32_bf16(af, bfr0, acc[mt][0], 0, 0, 0);
        acc[mt][1] = __builtin_amdgcn_mfma_f32_16x16x32_bf16(af, bfr1, acc[mt][1], 0, 0, 0);
      }
    }
  }
#pragma unroll
  for (int nt = 0; nt < 2; ++nt) {
    const int oc = oc0 + nt * 16 + lrow;
    const float bv = bias[oc];
    if constexpr (LAST) {
#pragma unroll
      for (int mt = 0; mt < 8; ++mt) {
        const int px = mt * 16 + lk * 4;
        float4 v = {acc[mt][nt][0] + bv, acc[mt][nt][1] + bv,
                    acc[mt][nt][2] + bv, acc[mt][nt][3] + bv};
        *reinterpret_cast<float4*>(outf + ((size_t)(b * 128 + oc) * HH + y) * WW + px) = v;
      }
    } else {
#pragma unroll
      for (int mt = 0; mt < 8; ++mt) {
#pragma unroll
        for (int m = 0; m < 4; ++m) {
          const int px = mt * 16 + lk * 4 + m;
          outq[((size_t)(b * HH + y) * WW + px) * 128 + oc] = f2bf(acc[mt][nt][m] + bv);
        }
      }
    }
  }
}

// ---------- final conv-transpose 128 -> 3: 2-row blocks, 256 threads ----------
__global__ __launch_bounds__(256, 3) void conv_out3(
    const float* __restrict__ in, const float* __restrict__ w,
    const float* __restrict__ bias, float* __restrict__ out) {
  __shared__ float s_in[16][4][130];
  __shared__ float s_w[128][28];
  const int tid = threadIdx.x;
  const int b = blockIdx.x >> 6;
  const int y0 = (blockIdx.x & 63) << 1;
  const int yloc = tid >> 7;
  const int x = tid & 127;
  const int y = y0 + yloc;
  for (int i = tid; i < 128 * 27; i += 256) {
    int ci = i / 27, rem = i % 27, oc = rem / 9, tap = rem % 9;
    int ky = tap / 3, kx = tap % 3;
    s_w[ci][tap * 3 + oc] = w[((ci * 3 + oc) * 3 + (2 - ky)) * 3 + (2 - kx)];
  }
  float acc[3] = {0.f, 0.f, 0.f};
#pragma unroll 1
  for (int ci0 = 0; ci0 < 128; ci0 += 16) {
    for (int i = tid; i < 16 * 520; i += 256) {
      int ci = i / 520;
      int rem = i - ci * 520;
      int r = rem / 130;
      int px = rem - r * 130;
      int yy = y0 + r - 1;
      float v = 0.f;
      if (yy >= 0 && yy < HH && px >= 1 && px <= 128)
        v = in[((b * 128 + ci0 + ci) * HH + yy) * WW + (px - 1)];
      s_in[ci][r][px] = v;
    }
    __syncthreads();
#pragma unroll 1
    for (int ci = 0; ci < 16; ++ci) {
#pragma unroll
      for (int r = 0; r < 3; ++r) {
        float i3[3] = {s_in[ci][yloc + r][x], s_in[ci][yloc + r][x + 1],
                       s_in[ci][yloc + r][x + 2]};
#pragma unroll
        for (int dx = 0; dx < 3; ++dx)
#pragma unroll
          for (int oc = 0; oc < 3; ++oc)
            acc[oc] += s_w[ci0 + ci][(r * 3 + dx) * 3 + oc] * i3[dx];
      }
    }
    __syncthreads();
  }
#pragma unroll
  for (int oc = 0; oc < 3; ++oc)
    out[((b * 3 + oc) * HH + y) * WW + x] = acc[oc] + bias[oc];
}

// ---------- finalize: loss + perplexity (fp64; runs before decoder) ----------
__global__ void finalize(const float* __restrict__ partial,
                         const int* __restrict__ counts, float* __restrict__ out) {
  __shared__ double redh[4], reds[4];
  const int tid = threadIdx.x;
  double h = 0.0;
  for (int k = tid; k < KK; k += 256) {
    double p = (double)counts[k] * (1.0 / (double)NPIX);
    h += p * log(p + 1e-10);
  }
  double s = 0.0;
  for (int i = tid; i < VQ_BLOCKS; i += 256) s += (double)partial[i];
  for (int off = 32; off; off >>= 1) {
    h += __shfl_down(h, off);
    s += __shfl_down(s, off);
  }
  if ((tid & 63) == 0) { redh[tid >> 6] = h; reds[tid >> 6] = s; }
  __syncthreads();
  if (tid == 0) {
    double Hs = redh[0] + redh[1] + redh[2] + redh[3];
    double Ss = reds[0] + reds[1] + reds[2] + reds[3];
    out[0] = (float)(0.25 * Ss * (1.0 / (double)NELEM));
    out[1 + XRECON] = (float)exp(-Hs);
  }
}

}  // namespace

extern "C" void kernel_launch(void* const* d_in, const int* in_sizes, int n_in,
                              void* d_out, int out_size, void* d_ws, size_t ws_size,
                              hipStream_t stream) {
  (void)in_sizes; (void)n_in; (void)out_size; (void)ws_size;
  const float* x       = (const float*)d_in[0];
  const float* enc_w0  = (const float*)d_in[1];
  const float* enc_b0  = (const float*)d_in[2];
  const float* enc_wh  = (const float*)d_in[3];
  const float* enc_bh  = (const float*)d_in[4];
  const float* pre_w   = (const float*)d_in[5];
  const float* pre_b   = (const float*)d_in[6];
  const float* codebook= (const float*)d_in[7];
  const float* dec_wh  = (const float*)d_in[8];
  const float* dec_bh  = (const float*)d_in[9];
  const float* dec_wl  = (const float*)d_in[10];
  const float* dec_bl  = (const float*)d_in[11];
  float* out = (float*)d_out;

  // Workspace: A, Bf = two NELEM fp32 buffers (256 MiB total).
  float* A = (float*)d_ws;
  float* Bf = A + NELEM;
  ushort* Q0 = (ushort*)Bf;
  ushort* Q1 = Q0 + NELEM;

  // Transient scratch in d_out's x_recon region (consumed before conv_out3).
  int* counts = (int*)(out + 1);
  float* partial = out + 1 + KK;
  float* wbuf = out + 4612;
  ushort* wb0 = (ushort*)(wbuf + 147456);
  ushort* wb1 = wb0 + 147456;
  ushort* wb2 = wb1 + 147456;

  const int LSTRIDE = 128 * 128 * 9;
  const int RGRID = NB * HH;       // 2048
  const int CGRID = NB * HH * 2;   // 4096
  const int WGRID = 576;

  zero_counts<<<1, 256, 0, stream>>>(counts);

  // encoder: layer-1 fp64; 128-convs fp32 chain acc via scalar-weight conv
  conv_l1<<<CGRID, 256, 0, stream>>>(x, enc_w0, enc_b0, A);
  repack_w<<<WGRID, 256, 0, stream>>>(enc_wh, wbuf);
  conv3x3_s<16><<<RGRID, 256, 0, stream>>>(A, wbuf, enc_bh, Bf);
  repack_w<<<WGRID, 256, 0, stream>>>(enc_wh + LSTRIDE, wbuf);
  conv3x3_s<16><<<RGRID, 256, 0, stream>>>(Bf, wbuf, enc_bh + 128, A);
  repack_w<<<WGRID, 256, 0, stream>>>(enc_wh + 2 * LSTRIDE, wbuf);
  conv3x3_s<16><<<RGRID, 256, 0, stream>>>(A, wbuf, enc_bh + 256, Bf);

  // pre-VQ 1x1 -> fp32 NHWC flat in A
  prevq_nhwc<<<CGRID, 256, 0, stream>>>(Bf, pre_w, pre_b, A);

  // decoder weight repacks (bf16, TRANS flip folded in)
  repack_wb16<<<WGRID, 256, 0, stream>>>(dec_wh, wb0);
  repack_wb16<<<WGRID, 256, 0, stream>>>(dec_wh + LSTRIDE, wb1);
  repack_wb16<<<WGRID, 256, 0, stream>>>(dec_wh + 2 * LSTRIDE, wb2);

  // VQ: fp32 BLAS-order scores (locked since r7); q -> Q0 (bf16 NHWC)
  vq_fused<<<VQ_BLOCKS, 256, 0, stream>>>(A, codebook, Q0, partial, counts);

  // loss + perplexity (before decoder/conv_out3 overwrite the scratch)
  finalize<<<1, 256, 0, stream>>>(partial, counts, out);

  // decoder: bf16 MFMA convs; last emits fp32 NCHW into A
  dec_mfma<false><<<RGRID, 256, 0, stream>>>(Q0, wb0, dec_bh, nullptr, Q1);
  dec_mfma<false><<<RGRID, 256, 0, stream>>>(Q1, wb1, dec_bh + 128, nullptr, Q0);
  dec_mfma<true><<<RGRID, 256, 0, stream>>>(Q0, wb2, dec_bh + 256, A, nullptr);
  conv_out3<<<NB * HH / 2, 256, 0, stream>>>(A, dec_wl, dec_bl, out + 1);
}

// Round 18
// 4703.021 us; speedup vs baseline: 1.1538x; 1.0074x over previous
//
#include <hip/hip_runtime.h>

namespace {

constexpr int NB = 16, HH = 128, WW = 128, KK = 512, DD = 128;
constexpr int NPIX = NB * HH * WW;        // 262144
constexpr int NELEM = NPIX * DD;          // 33554432
constexpr int XRECON = NB * 3 * HH * WW;  // 786432
constexpr int VQ_BLK_PX = 64;
constexpr int VQ_BLOCKS = NPIX / VQ_BLK_PX;  // 4096

using bf16x8 = __attribute__((ext_vector_type(8))) short;
using f32x4 = __attribute__((ext_vector_type(4))) float;

__device__ __forceinline__ ushort f2bf(float f) {
  unsigned u = __float_as_uint(f);
  return (ushort)((u + 0x7FFFu + ((u >> 16) & 1u)) >> 16);  // RNE
}

// ---------- zero the code-usage histogram (lives in d_out scratch) ----------
__global__ void zero_counts(int* __restrict__ counts) {
  const int t = threadIdx.x;
  counts[t] = 0;
  counts[t + 256] = 0;
}

// swizzle preserving 8B alignment at even px: phys = px + (px>>5)*4
__device__ __forceinline__ int swz(int px) { return px + ((px >> 5) << 2); }

// ---------- fp32 weight repack: w -> wr[ci][tap][oc] (encoder) ----------
__global__ void repack_w(const float* __restrict__ w, float* __restrict__ wr) {
  int i = blockIdx.x * 256 + threadIdx.x;  // over 128*9*128
  int oc = i & 127;
  int tap = (i >> 7) % 9;
  int ci = i / (9 * 128);
  wr[i] = w[(oc * 128 + ci) * 9 + tap];
}

// ---------- bf16 weight repack (decoder, TRANS flip): wr[tap][ci/8][oc][8] ----------
__global__ void repack_wb16(const float* __restrict__ w, ushort* __restrict__ wr) {
  int i = blockIdx.x * 256 + threadIdx.x;  // 9*16*128*8 = 147456
  int j = i & 7;
  int oc = (i >> 3) & 127;
  int cib = (i >> 10) & 15;
  int tap = i >> 14;
  int ci = cib * 8 + j;
  int ky = tap / 3, kx = tap % 3;
  float v = w[((size_t)ci * 128 + oc) * 9 + (2 - ky) * 3 + (2 - kx)];
  wr[i] = f2bf(v);
}

// ---------- 3x3 conv 128->128 fp32, scalar-weight path, 2-row blocks ----------
// Block: 2 rows x 128 px x 64 oc; 4 waves, wave owns 16 oc; lane owns px pair
// on BOTH rows (4 outputs, acc[16][4]). Weight s_load per ci halves vs r17.
// Per-output FMA chain ci0->ci->r->dx ascending: BIT-IDENTICAL to r9-r17
// (output row `row` reads window row `row+r`; loop nesting unchanged).
template <int CT>
__global__ __launch_bounds__(256, 4) void conv3x3_s2(
    const float* __restrict__ in, const float* __restrict__ wr,
    const float* __restrict__ bias, float* __restrict__ out) {
  __shared__ __align__(16) float s_in[CT][4][148];  // rows y0-1..y0+2
  const int tid = threadIdx.x;
  const int ocb = blockIdx.x & 1;
  const int y0 = ((blockIdx.x >> 1) & 63) << 1;
  const int b = blockIdx.x >> 7;
  const int lane = tid & 63;
  const int wv = __builtin_amdgcn_readfirstlane(tid >> 6);
  const int oc0 = ocb * 64 + wv * 16;
  const int px0 = lane << 1;

  float acc[16][4];  // [oc][row*2+px]
#pragma unroll
  for (int k = 0; k < 16; ++k)
#pragma unroll
    for (int p = 0; p < 4; ++p) acc[k][p] = 0.f;

  const int f_lo = swz(px0);
  const int f_hi = swz(px0 + 2);

#pragma unroll 1
  for (int ci0 = 0; ci0 < 128; ci0 += CT) {
    for (int i = tid; i < CT * 520; i += 256) {
      int ci = i / 520;
      int rem = i - ci * 520;
      int r = rem / 130;
      int px = rem - r * 130;
      int yy = y0 + r - 1;
      int xx = px - 1;
      float v = 0.f;
      if (yy >= 0 && yy < HH && xx >= 0 && xx < WW)
        v = in[((b * 128 + ci0 + ci) * HH + yy) * WW + xx];
      s_in[ci][r][swz(px)] = v;
    }
    __syncthreads();
#pragma unroll 1
    for (int ci = 0; ci < CT; ++ci) {
      float ind[4][4];  // [window row][m] input at x = px0 - 1 + m
#pragma unroll
      for (int r = 0; r < 4; ++r) {
        float2 a = *reinterpret_cast<const float2*>(&s_in[ci][r][f_lo]);
        float2 c = *reinterpret_cast<const float2*>(&s_in[ci][r][f_hi]);
        ind[r][0] = a.x; ind[r][1] = a.y; ind[r][2] = c.x; ind[r][3] = c.y;
      }
      const float* wp = wr + (size_t)(ci0 + ci) * 9 * 128 + oc0;
#pragma unroll
      for (int r = 0; r < 3; ++r) {
#pragma unroll
        for (int dx = 0; dx < 3; ++dx) {
          const float* wt = wp + (r * 3 + dx) * 128;
          float ws[16];
#pragma unroll
          for (int k = 0; k < 16; ++k) ws[k] = wt[k];
          float a0 = ind[r][dx], a1 = ind[r][dx + 1];        // output row y0
          float b0 = ind[r + 1][dx], b1 = ind[r + 1][dx + 1]; // output row y0+1
#pragma unroll
          for (int k = 0; k < 16; ++k) {
            acc[k][0] = __fmaf_rn(ws[k], a0, acc[k][0]);
            acc[k][1] = __fmaf_rn(ws[k], a1, acc[k][1]);
            acc[k][2] = __fmaf_rn(ws[k], b0, acc[k][2]);
            acc[k][3] = __fmaf_rn(ws[k], b1, acc[k][3]);
          }
        }
      }
    }
    __syncthreads();
  }
#pragma unroll
  for (int k = 0; k < 16; ++k) {
    int oc = oc0 + k;
    float bv = bias[oc];
    float2 v0 = {acc[k][0] + bv, acc[k][1] + bv};
    float2 v1 = {acc[k][2] + bv, acc[k][3] + bv};
    *reinterpret_cast<float2*>(out + ((b * 128 + oc) * HH + y0) * WW + px0) = v0;
    *reinterpret_cast<float2*>(out + ((b * 128 + oc) * HH + y0 + 1) * WW + px0) = v1;
  }
}

// ---------- layer-1 conv 3->128, fp64 acc (r14-proven, spill-free) ----------
__global__ __launch_bounds__(256, 3) void conv_l1(
    const float* __restrict__ in, const float* __restrict__ w,
    const float* __restrict__ bias, float* __restrict__ out) {
  __shared__ __align__(16) double s_in[3][3][74];
  __shared__ __align__(16) float s_w[27][132];
  const int tid = threadIdx.x;
  const int b = blockIdx.x >> 8;
  const int y = (blockIdx.x >> 1) & 127;
  const int x0base = (blockIdx.x & 1) << 6;
  const int ocg = tid >> 3;
  const int pxg = tid & 7;
  const int x0 = pxg * 8;
  const int f0 = pxg * 9;

  double acc[4][8];
#pragma unroll
  for (int k = 0; k < 4; ++k)
#pragma unroll
    for (int p = 0; p < 8; ++p) acc[k][p] = 0.0;

  for (int i = tid; i < 3 * 198; i += 256) {
    int ci = i / 198;
    int rem = i - ci * 198;
    int r = rem / 66;
    int px = rem - r * 66;
    int yy = y + r - 1;
    int xx = x0base + px - 1;
    float v = 0.f;
    if (yy >= 0 && yy < HH && xx >= 0 && xx < WW)
      v = in[((b * 3 + ci) * HH + yy) * WW + xx];
    s_in[ci][r][px + (px >> 3)] = (double)v;
  }
  for (int i = tid; i < 128 * 27; i += 256) {
    int oc = i / 27;
    int j = i - oc * 27;
    s_w[j][oc] = w[oc * 27 + j];
  }
  __syncthreads();
#pragma unroll 1
  for (int ci = 0; ci < 3; ++ci) {
#pragma unroll
    for (int r = 0; r < 3; ++r) {
      double ind[10];
#pragma unroll
      for (int m = 0; m < 8; ++m) ind[m] = s_in[ci][r][f0 + m];
      ind[8] = s_in[ci][r][f0 + 9];
      ind[9] = s_in[ci][r][f0 + 10];
#pragma unroll
      for (int dx = 0; dx < 3; ++dx) {
        float4 w4 = *reinterpret_cast<const float4*>(&s_w[ci * 9 + r * 3 + dx][ocg * 4]);
        double wd[4] = {(double)w4.x, (double)w4.y, (double)w4.z, (double)w4.w};
#pragma unroll
        for (int k = 0; k < 4; ++k)
#pragma unroll
          for (int p = 0; p < 8; ++p) acc[k][p] += wd[k] * ind[p + dx];
      }
    }
  }
#pragma unroll
  for (int k = 0; k < 4; ++k) {
    int oc = ocg * 4 + k;
    double bv = (double)bias[oc];
    float* op = out + ((b * 128 + oc) * HH + y) * WW + x0base + x0;
    float4 v = {(float)(acc[k][0] + bv), (float)(acc[k][1] + bv),
                (float)(acc[k][2] + bv), (float)(acc[k][3] + bv)};
    float4 v2 = {(float)(acc[k][4] + bv), (float)(acc[k][5] + bv),
                 (float)(acc[k][6] + bv), (float)(acc[k][7] + bv)};
    *reinterpret_cast<float4*>(op) = v;
    *reinterpret_cast<float4*>(op + 4) = v2;
  }
}

// ---------- 1x1 conv (pre-VQ), fp32 chain acc (r14-proven) ----------
__global__ __launch_bounds__(256, 3) void prevq_nhwc(
    const float* __restrict__ in, const float* __restrict__ wmat,
    const float* __restrict__ bias, float* __restrict__ flat) {
  __shared__ __align__(16) float s_z[32][68];
  __shared__ __align__(16) float s_w[32][132];
  const int tid = threadIdx.x;
  const int b = blockIdx.x >> 8;
  const int y = (blockIdx.x >> 1) & 127;
  const int x0base = (blockIdx.x & 1) << 6;
  const int ocg = tid >> 3;
  const int pxg = tid & 7;
  float acc[4][8];
#pragma unroll
  for (int k = 0; k < 4; ++k)
#pragma unroll
    for (int p = 0; p < 8; ++p) acc[k][p] = 0.f;

#pragma unroll 1
  for (int c0 = 0; c0 < 128; c0 += 32) {
    for (int t = tid; t < 32 * 64; t += 256) {
      int c = t >> 6, px = t & 63;
      s_z[c][px] = in[((b * 128 + c0 + c) * HH + y) * WW + x0base + px];
    }
    for (int t = tid; t < 32 * 128; t += 256) {
      int o = t >> 5, c = t & 31;
      s_w[c][o] = wmat[o * 128 + c0 + c];
    }
    __syncthreads();
#pragma unroll 1
    for (int c = 0; c < 32; ++c) {
      float f8[8];
#pragma unroll
      for (int p = 0; p < 8; ++p) f8[p] = s_z[c][pxg * 8 + p];
      float4 w4 = *reinterpret_cast<const float4*>(&s_w[c][ocg * 4]);
      float wd[4] = {w4.x, w4.y, w4.z, w4.w};
#pragma unroll
      for (int k = 0; k < 4; ++k)
#pragma unroll
        for (int p = 0; p < 8; ++p) acc[k][p] = __fmaf_rn(wd[k], f8[p], acc[k][p]);
    }
    __syncthreads();
  }
  float bv[4];
#pragma unroll
  for (int k = 0; k < 4; ++k) bv[k] = bias[ocg * 4 + k];
  const int pixbase = (b * HH + y) * WW + x0base + pxg * 8;
#pragma unroll
  for (int p = 0; p < 8; ++p) {
    float* op = flat + (pixbase + p) * DD + ocg * 4;
#pragma unroll
    for (int k = 0; k < 4; ++k) op[k] = __fadd_rn(acc[k][p], bv[k]);
  }
}

// ---------- numpy-faithful fp32 sum of squares over 128 elems ----------
__device__ __forceinline__ float pairwise8_sq(const float* v) {
  float r[8];
#pragma unroll
  for (int j = 0; j < 8; ++j) r[j] = __fmul_rn(v[j], v[j]);
#pragma unroll
  for (int i = 8; i < 128; i += 8)
#pragma unroll
    for (int j = 0; j < 8; ++j) r[j] = __fadd_rn(r[j], __fmul_rn(v[i + j], v[i + j]));
  return __fadd_rn(__fadd_rn(__fadd_rn(r[0], r[1]), __fadd_rn(r[2], r[3])),
                   __fadd_rn(__fadd_rn(r[4], r[5]), __fadd_rn(r[6], r[7])));
}

// ---------- fused VQ, reference-faithful fp32 scoring (DO NOT CHANGE MATH) ----------
constexpr int SF_OFF = 0;
constexpr int SC_OFF = 33792;
constexpr int SRB_OFF = SC_OFF;
constexpr int SRI_OFF = SC_OFF + 4352;
constexpr int SCN_OFF = SC_OFF + 33792;
constexpr int SZN_OFF = SCN_OFF + 256;
constexpr int SIDX_OFF = SZN_OFF + 256;
constexpr int SRED_OFF = SIDX_OFF + 256;
constexpr int SMEM_BYTES = SRED_OFF + 32;

__global__ __launch_bounds__(256, 2) void vq_fused(
    const float* __restrict__ flat, const float* __restrict__ codebook,
    ushort* __restrict__ q16, float* __restrict__ partial, int* __restrict__ counts) {
  __shared__ __align__(16) char smem[SMEM_BYTES];
  float (*s_f)[132] = reinterpret_cast<float (*)[132]>(smem + SF_OFF);
  float (*s_c)[132] = reinterpret_cast<float (*)[132]>(smem + SC_OFF);
  float (*s_rb)[4][17] = reinterpret_cast<float (*)[4][17]>(smem + SRB_OFF);
  int (*s_ri)[4][17] = reinterpret_cast<int (*)[4][17]>(smem + SRI_OFF);
  float* s_cn = reinterpret_cast<float*>(smem + SCN_OFF);
  float* s_zn = reinterpret_cast<float*>(smem + SZN_OFF);
  int* s_idx = reinterpret_cast<int*>(smem + SIDX_OFF);
  double* s_red = reinterpret_cast<double*>(smem + SRED_OFF);

  const int tid = threadIdx.x;
  const int n0 = blockIdx.x * VQ_BLK_PX;
  const int pxg = tid & 15;
  const int cg = tid >> 4;

  for (int t = tid; t < VQ_BLK_PX * 128; t += 256) {
    int i = t >> 7, d = t & 127;
    s_f[i][d] = flat[(n0 + i) * DD + d];
  }
  __syncthreads();
  if (tid < VQ_BLK_PX) s_zn[tid] = pairwise8_sq(&s_f[tid][0]);

  float best[4] = {3.402823466e+38f, 3.402823466e+38f,
                   3.402823466e+38f, 3.402823466e+38f};
  int bi[4] = {0, 0, 0, 0};

#pragma unroll 1
  for (int c0 = 0; c0 < KK; c0 += 64) {
    for (int t = tid; t < 64 * 128; t += 256) {
      int cc = t >> 7, d = t & 127;
      s_c[cc][d] = codebook[(c0 + cc) * DD + d];
    }
    __syncthreads();
    if (tid < 64) s_cn[tid] = pairwise8_sq(&s_c[tid][0]);
    __syncthreads();
    float acc[4][4];
#pragma unroll
    for (int i = 0; i < 4; ++i)
#pragma unroll
      for (int j = 0; j < 4; ++j) acc[i][j] = 0.f;
#pragma unroll 1
    for (int d0 = 0; d0 < 128; d0 += 4) {
      float4 f4[4], c4[4];
#pragma unroll
      for (int i = 0; i < 4; ++i)
        f4[i] = *reinterpret_cast<const float4*>(&s_f[pxg * 4 + i][d0]);
#pragma unroll
      for (int j = 0; j < 4; ++j)
        c4[j] = *reinterpret_cast<const float4*>(&s_c[cg * 4 + j][d0]);
#pragma unroll
      for (int i = 0; i < 4; ++i) {
#pragma unroll
        for (int j = 0; j < 4; ++j) {
          acc[i][j] = __fmaf_rn(f4[i].x, c4[j].x, acc[i][j]);
          acc[i][j] = __fmaf_rn(f4[i].y, c4[j].y, acc[i][j]);
          acc[i][j] = __fmaf_rn(f4[i].z, c4[j].z, acc[i][j]);
          acc[i][j] = __fmaf_rn(f4[i].w, c4[j].w, acc[i][j]);
        }
      }
    }
#pragma unroll
    for (int i = 0; i < 4; ++i)
#pragma unroll
      for (int j = 0; j < 4; ++j) {
        float score = __fsub_rn(__fadd_rn(s_zn[pxg * 4 + i], s_cn[cg * 4 + j]),
                                __fmul_rn(2.0f, acc[i][j]));
        int code = c0 + cg * 4 + j;
        if (score < best[i]) { best[i] = score; bi[i] = code; }
      }
    __syncthreads();
  }
#pragma unroll
  for (int i = 0; i < 4; ++i) {
    s_rb[pxg][i][cg] = best[i];
    s_ri[pxg][i][cg] = bi[i];
  }
  __syncthreads();
  if (tid < 16) {
    for (int i = 0; i < 4; ++i) {
      float m = s_rb[tid][i][0];
      int mi = s_ri[tid][i][0];
      for (int g = 1; g < 16; ++g) {
        float v = s_rb[tid][i][g];
        int vi = s_ri[tid][i][g];
        if (v < m || (v == m && vi < mi)) { m = v; mi = vi; }
      }
      s_idx[tid * 4 + i] = mi;
    }
  }
  __syncthreads();
  if (tid < VQ_BLK_PX) atomicAdd(&counts[s_idx[tid]], 1);

  // gather -> q (bf16 NHWC) + fp64 SSE vs fp32 z (still in s_f)
  const int px = tid & 63;
  const int dg = tid >> 6;
  const int n = n0 + px;
  const int k = s_idx[px];
  const float* crow = codebook + k * DD + dg * 32;
  ushort* qb = q16 + (size_t)n * 128 + dg * 32;
  double s = 0.0;
#pragma unroll 4
  for (int j = 0; j < 32; ++j) {
    float e = crow[j];
    double dd = (double)e - (double)s_f[px][dg * 32 + j];
    s += dd * dd;
    qb[j] = f2bf(e);
  }
  for (int off = 32; off; off >>= 1) s += __shfl_down(s, off);
  if ((tid & 63) == 0) s_red[tid >> 6] = s;
  __syncthreads();
  if (tid == 0)
    partial[blockIdx.x] = (float)(s_red[0] + s_red[1] + s_red[2] + s_red[3]);
}

// ---------- decoder 3x3 conv via bf16 MFMA (r15-proven, unchanged) ----------
template <bool LAST>
__global__ __launch_bounds__(256, 4) void dec_mfma(
    const ushort* __restrict__ inq, const ushort* __restrict__ wb,
    const float* __restrict__ bias, float* __restrict__ outf,
    ushort* __restrict__ outq) {
  const int b = blockIdx.x >> 7;
  const int y = blockIdx.x & 127;
  const int lane = threadIdx.x & 63;
  const int wv = threadIdx.x >> 6;
  const int oc0 = wv << 5;
  const int lrow = lane & 15;
  const int lk = lane >> 4;

  f32x4 acc[8][2];
#pragma unroll
  for (int mt = 0; mt < 8; ++mt)
#pragma unroll
    for (int nt = 0; nt < 2; ++nt) acc[mt][nt] = (f32x4){0.f, 0.f, 0.f, 0.f};

#pragma unroll 1
  for (int tap = 0; tap < 9; ++tap) {
    const int ky = tap / 3, kx = tap % 3;
    const int yy = y + ky - 1;
    const bool yok = (yy >= 0) && (yy < HH);
    const ushort* wtap = wb + tap * (16 * 128 * 8);
    const ushort* rowp = inq + ((size_t)(b * HH + yy) * WW) * 128;
#pragma unroll 1
    for (int cb = 0; cb < 4; ++cb) {
      const int cib = cb * 4 + lk;
      bf16x8 bfr0 = *reinterpret_cast<const bf16x8*>(wtap + ((size_t)(cib * 128) + oc0 + lrow) * 8);
      bf16x8 bfr1 = *reinterpret_cast<const bf16x8*>(wtap + ((size_t)(cib * 128) + oc0 + 16 + lrow) * 8);
#pragma unroll
      for (int mt = 0; mt < 8; ++mt) {
        const int xx = mt * 16 + lrow + kx - 1;
        bf16x8 af = {0, 0, 0, 0, 0, 0, 0, 0};
        if (yok && xx >= 0 && xx < WW)
          af = *reinterpret_cast<const bf16x8*>(rowp + (size_t)xx * 128 + cib * 8);
        acc[mt][0] = __builtin_amdgcn_mfma_f32_16x16x32_bf16(af, bfr0, acc[mt][0], 0, 0, 0);
        acc[mt][1] = __builtin_amdgcn_mfma_f32_16x16x32_bf16(af, bfr1, acc[mt][1], 0, 0, 0);
      }
    }
  }
#pragma unroll
  for (int nt = 0; nt < 2; ++nt) {
    const int oc = oc0 + nt * 16 + lrow;
    const float bv = bias[oc];
    if constexpr (LAST) {
#pragma unroll
      for (int mt = 0; mt < 8; ++mt) {
        const int px = mt * 16 + lk * 4;
        float4 v = {acc[mt][nt][0] + bv, acc[mt][nt][1] + bv,
                    acc[mt][nt][2] + bv, acc[mt][nt][3] + bv};
        *reinterpret_cast<float4*>(outf + ((size_t)(b * 128 + oc) * HH + y) * WW + px) = v;
      }
    } else {
#pragma unroll
      for (int mt = 0; mt < 8; ++mt) {
#pragma unroll
        for (int m = 0; m < 4; ++m) {
          const int px = mt * 16 + lk * 4 + m;
          outq[((size_t)(b * HH + y) * WW + px) * 128 + oc] = f2bf(acc[mt][nt][m] + bv);
        }
      }
    }
  }
}

// ---------- final conv-transpose 128 -> 3: 2-row blocks, 256 threads ----------
__global__ __launch_bounds__(256, 3) void conv_out3(
    const float* __restrict__ in, const float* __restrict__ w,
    const float* __restrict__ bias, float* __restrict__ out) {
  __shared__ float s_in[16][4][130];
  __shared__ float s_w[128][28];
  const int tid = threadIdx.x;
  const int b = blockIdx.x >> 6;
  const int y0 = (blockIdx.x & 63) << 1;
  const int yloc = tid >> 7;
  const int x = tid & 127;
  const int y = y0 + yloc;
  for (int i = tid; i < 128 * 27; i += 256) {
    int ci = i / 27, rem = i % 27, oc = rem / 9, tap = rem % 9;
    int ky = tap / 3, kx = tap % 3;
    s_w[ci][tap * 3 + oc] = w[((ci * 3 + oc) * 3 + (2 - ky)) * 3 + (2 - kx)];
  }
  float acc[3] = {0.f, 0.f, 0.f};
#pragma unroll 1
  for (int ci0 = 0; ci0 < 128; ci0 += 16) {
    for (int i = tid; i < 16 * 520; i += 256) {
      int ci = i / 520;
      int rem = i - ci * 520;
      int r = rem / 130;
      int px = rem - r * 130;
      int yy = y0 + r - 1;
      float v = 0.f;
      if (yy >= 0 && yy < HH && px >= 1 && px <= 128)
        v = in[((b * 128 + ci0 + ci) * HH + yy) * WW + (px - 1)];
      s_in[ci][r][px] = v;
    }
    __syncthreads();
#pragma unroll 1
    for (int ci = 0; ci < 16; ++ci) {
#pragma unroll
      for (int r = 0; r < 3; ++r) {
        float i3[3] = {s_in[ci][yloc + r][x], s_in[ci][yloc + r][x + 1],
                       s_in[ci][yloc + r][x + 2]};
#pragma unroll
        for (int dx = 0; dx < 3; ++dx)
#pragma unroll
          for (int oc = 0; oc < 3; ++oc)
            acc[oc] += s_w[ci0 + ci][(r * 3 + dx) * 3 + oc] * i3[dx];
      }
    }
    __syncthreads();
  }
#pragma unroll
  for (int oc = 0; oc < 3; ++oc)
    out[((b * 3 + oc) * HH + y) * WW + x] = acc[oc] + bias[oc];
}

// ---------- finalize: loss + perplexity (fp64; runs before decoder) ----------
__global__ void finalize(const float* __restrict__ partial,
                         const int* __restrict__ counts, float* __restrict__ out) {
  __shared__ double redh[4], reds[4];
  const int tid = threadIdx.x;
  double h = 0.0;
  for (int k = tid; k < KK; k += 256) {
    double p = (double)counts[k] * (1.0 / (double)NPIX);
    h += p * log(p + 1e-10);
  }
  double s = 0.0;
  for (int i = tid; i < VQ_BLOCKS; i += 256) s += (double)partial[i];
  for (int off = 32; off; off >>= 1) {
    h += __shfl_down(h, off);
    s += __shfl_down(s, off);
  }
  if ((tid & 63) == 0) { redh[tid >> 6] = h; reds[tid >> 6] = s; }
  __syncthreads();
  if (tid == 0) {
    double Hs = redh[0] + redh[1] + redh[2] + redh[3];
    double Ss = reds[0] + reds[1] + reds[2] + reds[3];
    out[0] = (float)(0.25 * Ss * (1.0 / (double)NELEM));
    out[1 + XRECON] = (float)exp(-Hs);
  }
}

}  // namespace

extern "C" void kernel_launch(void* const* d_in, const int* in_sizes, int n_in,
                              void* d_out, int out_size, void* d_ws, size_t ws_size,
                              hipStream_t stream) {
  (void)in_sizes; (void)n_in; (void)out_size; (void)ws_size;
  const float* x       = (const float*)d_in[0];
  const float* enc_w0  = (const float*)d_in[1];
  const float* enc_b0  = (const float*)d_in[2];
  const float* enc_wh  = (const float*)d_in[3];
  const float* enc_bh  = (const float*)d_in[4];
  const float* pre_w   = (const float*)d_in[5];
  const float* pre_b   = (const float*)d_in[6];
  const float* codebook= (const float*)d_in[7];
  const float* dec_wh  = (const float*)d_in[8];
  const float* dec_bh  = (const float*)d_in[9];
  const float* dec_wl  = (const float*)d_in[10];
  const float* dec_bl  = (const float*)d_in[11];
  float* out = (float*)d_out;

  // Workspace: A, Bf = two NELEM fp32 buffers (256 MiB total).
  float* A = (float*)d_ws;
  float* Bf = A + NELEM;
  ushort* Q0 = (ushort*)Bf;
  ushort* Q1 = Q0 + NELEM;

  // Transient scratch in d_out's x_recon region (consumed before conv_out3).
  int* counts = (int*)(out + 1);
  float* partial = out + 1 + KK;
  float* wbuf = out + 4612;
  ushort* wb0 = (ushort*)(wbuf + 147456);
  ushort* wb1 = wb0 + 147456;
  ushort* wb2 = wb1 + 147456;

  const int LSTRIDE = 128 * 128 * 9;
  const int RGRID = NB * HH;       // 2048 (dec_mfma rows; conv3x3_s2 also 2048)
  const int CGRID = NB * HH * 2;   // 4096
  const int WGRID = 576;

  zero_counts<<<1, 256, 0, stream>>>(counts);

  // encoder: layer-1 fp64; 128-convs fp32 chain acc via scalar-weight conv
  conv_l1<<<CGRID, 256, 0, stream>>>(x, enc_w0, enc_b0, A);
  repack_w<<<WGRID, 256, 0, stream>>>(enc_wh, wbuf);
  conv3x3_s2<16><<<RGRID, 256, 0, stream>>>(A, wbuf, enc_bh, Bf);
  repack_w<<<WGRID, 256, 0, stream>>>(enc_wh + LSTRIDE, wbuf);
  conv3x3_s2<16><<<RGRID, 256, 0, stream>>>(Bf, wbuf, enc_bh + 128, A);
  repack_w<<<WGRID, 256, 0, stream>>>(enc_wh + 2 * LSTRIDE, wbuf);
  conv3x3_s2<16><<<RGRID, 256, 0, stream>>>(A, wbuf, enc_bh + 256, Bf);

  // pre-VQ 1x1 -> fp32 NHWC flat in A
  prevq_nhwc<<<CGRID, 256, 0, stream>>>(Bf, pre_w, pre_b, A);

  // decoder weight repacks (bf16, TRANS flip folded in)
  repack_wb16<<<WGRID, 256, 0, stream>>>(dec_wh, wb0);
  repack_wb16<<<WGRID, 256, 0, stream>>>(dec_wh + LSTRIDE, wb1);
  repack_wb16<<<WGRID, 256, 0, stream>>>(dec_wh + 2 * LSTRIDE, wb2);

  // VQ: fp32 BLAS-order scores (locked since r7); q -> Q0 (bf16 NHWC)
  vq_fused<<<VQ_BLOCKS, 256, 0, stream>>>(A, codebook, Q0, partial, counts);

  // loss + perplexity (before decoder/conv_out3 overwrite the scratch)
  finalize<<<1, 256, 0, stream>>>(partial, counts, out);

  // decoder: bf16 MFMA convs; last emits fp32 NCHW into A
  dec_mfma<false><<<RGRID, 256, 0, stream>>>(Q0, wb0, dec_bh, nullptr, Q1);
  dec_mfma<false><<<RGRID, 256, 0, stream>>>(Q1, wb1, dec_bh + 128, nullptr, Q0);
  dec_mfma<true><<<RGRID, 256, 0, stream>>>(Q0, wb2, dec_bh + 256, A, nullptr);
  conv_out3<<<NB * HH / 2, 256, 0, stream>>>(A, dec_wl, dec_bl, out + 1);
}